// Round 3
// baseline (718.073 us; speedup 1.0000x reference)
//
#include <hip/hip_runtime.h>
#include <hip/hip_bf16.h>

// Problem constants (from reference setup_inputs)
#define BATCH 8
#define CHAN 128
#define CLASSES 21
#define HW 65536            // 256*256
#define EPS 1e-8f

// ---------------------------------------------------------------------------
// Pass 0: pack gt int32 -> uint8 (4x smaller label stream, L2-resident) and
// per-(b,class) pixel counts. Per-LANE privatized count bins: addr = cls*64 +
// lane -> all 64 addresses distinct within a wave instr (no same-address
// serialization), bank = lane%32 -> uniform 2-way (free). Grid: (HW/1024, B).
__global__ __launch_bounds__(256) void k_pack_count(
    const int* __restrict__ gt, unsigned char* __restrict__ packed,
    int* __restrict__ counts) {
    __shared__ int lc[CLASSES * 64];
    const int t = threadIdx.x;
    const int lane = t & 63;
    const int b = blockIdx.y;
    const size_t base = (size_t)b * HW + (size_t)blockIdx.x * 1024;

    for (int i = t; i < CLASSES * 64; i += 256) lc[i] = 0;
    __syncthreads();

    int4 g = ((const int4*)(gt + base))[t];
    uchar4 pk = make_uchar4((unsigned char)g.x, (unsigned char)g.y,
                            (unsigned char)g.z, (unsigned char)g.w);
    ((uchar4*)(packed + base))[t] = pk;
    atomicAdd(&lc[g.x * 64 + lane], 1);
    atomicAdd(&lc[g.y * 64 + lane], 1);
    atomicAdd(&lc[g.z * 64 + lane], 1);
    atomicAdd(&lc[g.w * 64 + lane], 1);
    __syncthreads();

    if (t < 64) {  // wave 0: butterfly-reduce each class's 64 bins
        #pragma unroll
        for (int cls = 0; cls < CLASSES; ++cls) {
            int s = lc[cls * 64 + t];
            #pragma unroll
            for (int off = 32; off >= 1; off >>= 1) s += __shfl_xor(s, off, 64);
            if (t == 0) atomicAdd(&counts[b * CLASSES + cls], s);
        }
    }
}

// ---------------------------------------------------------------------------
// Pass 1: segment sums. Per-LANE privatized f32 bins + ds_add_f32 (no-return
// LDS atomic): 1 LDS instr per pixel, no RMW dependency chain, no same-address
// collisions, 2-way banks (free). Tail: wave-0 shuffle butterfly, 21 global
// atomics per block. Grid: (4, CHAN, BATCH), block 256.
__global__ __launch_bounds__(256) void k_reduce(
    const float* __restrict__ img, const unsigned char* __restrict__ packed,
    float* __restrict__ sums) {
    __shared__ float acc[CLASSES * 64];
    const int t = threadIdx.x;
    const int lane = t & 63;
    const int chunk = blockIdx.x;   // 0..3
    const int c = blockIdx.y;
    const int b = blockIdx.z;

    for (int i = t; i < CLASSES * 64; i += 256) acc[i] = 0.0f;
    __syncthreads();

    const float4* __restrict__ imgp =
        (const float4*)(img + ((size_t)(b * CHAN + c)) * HW + (size_t)chunk * (HW / 4));
    const uchar4* __restrict__ gtp =
        (const uchar4*)(packed + (size_t)b * HW + (size_t)chunk * (HW / 4));

    #pragma unroll 4
    for (int i = t; i < (HW / 4) / 4; i += 256) {   // 16 iters
        float4 v = imgp[i];
        uchar4 g = gtp[i];
        unsafeAtomicAdd(&acc[(int)g.x * 64 + lane], v.x);
        unsafeAtomicAdd(&acc[(int)g.y * 64 + lane], v.y);
        unsafeAtomicAdd(&acc[(int)g.z * 64 + lane], v.z);
        unsafeAtomicAdd(&acc[(int)g.w * 64 + lane], v.w);
    }
    __syncthreads();

    if (t < 64) {  // wave 0
        #pragma unroll
        for (int cls = 0; cls < CLASSES; ++cls) {
            float s = acc[cls * 64 + t];
            #pragma unroll
            for (int off = 32; off >= 1; off >>= 1) s += __shfl_xor(s, off, 64);
            if (t == 0)
                unsafeAtomicAdd(&sums[((size_t)b * CLASSES + cls) * CHAN + c], s);
        }
    }
}

// ---------------------------------------------------------------------------
// Tiny: means[b][cls][c] = sums / (count + eps).
__global__ __launch_bounds__(256) void k_means(
    const float* __restrict__ sums, const int* __restrict__ counts,
    float* __restrict__ means) {
    int i = blockIdx.x * 256 + threadIdx.x;
    if (i < BATCH * CLASSES * CHAN)
        means[i] = sums[i] / ((float)counts[i / CHAN] + EPS);
}

// ---------------------------------------------------------------------------
// Pass 2: 4 channels per block. m4[cls] = float4 of 4 channel means -> one
// ds_read_b128 serves 4 output elements. u8 labels (L2). 4 coalesced float4
// store streams. Grid: (16, CHAN/4, BATCH), block 256.
__global__ __launch_bounds__(256) void k_gather(
    const unsigned char* __restrict__ packed, const float* __restrict__ means,
    float* __restrict__ out) {
    __shared__ float4 m4[CLASSES];
    const int t = threadIdx.x;
    const int chunk = blockIdx.x;        // 0..15
    const int c0 = blockIdx.y * 4;
    const int b = blockIdx.z;
    const int PIX = HW / 16;             // 4096 pixels per block

    if (t < CLASSES * 4) {
        int cls = t >> 2, j = t & 3;
        ((float*)m4)[t] = means[((size_t)b * CLASSES + cls) * CHAN + c0 + j];
    }
    __syncthreads();

    const uchar4* __restrict__ gtp =
        (const uchar4*)(packed + (size_t)b * HW + (size_t)chunk * PIX);
    float* __restrict__ outbase =
        out + ((size_t)(b * CHAN + c0)) * HW + (size_t)chunk * PIX;

    for (int i = t; i < PIX / 4; i += 256) {   // 4 iters
        uchar4 g = gtp[i];
        float4 mx = m4[g.x], my = m4[g.y], mz = m4[g.z], mw = m4[g.w];
        float4 o0 = make_float4(mx.x, my.x, mz.x, mw.x);
        float4 o1 = make_float4(mx.y, my.y, mz.y, mw.y);
        float4 o2 = make_float4(mx.z, my.z, mz.z, mw.z);
        float4 o3 = make_float4(mx.w, my.w, mz.w, mw.w);
        ((float4*)(outbase          ))[i] = o0;
        ((float4*)(outbase +     HW))[i] = o1;
        ((float4*)(outbase + 2 * HW))[i] = o2;
        ((float4*)(outbase + 3 * HW))[i] = o3;
    }
}

extern "C" void kernel_launch(void* const* d_in, const int* in_sizes, int n_in,
                              void* d_out, int out_size, void* d_ws, size_t ws_size,
                              hipStream_t stream) {
    const float* img = (const float*)d_in[0];
    const int* gt = (const int*)d_in[1];
    float* out = (float*)d_out;

    // Workspace: sums f32[B*CLS*CHAN] | counts i32[B*CLS] | means f32[B*CLS*CHAN] | packed u8[B*HW]
    size_t off = 0;
    float* sums = (float*)d_ws;
    off += (size_t)BATCH * CLASSES * CHAN * sizeof(float);
    int* counts = (int*)((char*)d_ws + off);
    off += (size_t)BATCH * CLASSES * sizeof(int);
    float* means = (float*)((char*)d_ws + off);
    off += (size_t)BATCH * CLASSES * CHAN * sizeof(float);
    off = (off + 255) & ~(size_t)255;
    unsigned char* packed = (unsigned char*)d_ws + off;

    size_t zero_bytes = (size_t)BATCH * CLASSES * CHAN * sizeof(float)
                      + (size_t)BATCH * CLASSES * sizeof(int);
    hipMemsetAsync(d_ws, 0, zero_bytes, stream);

    dim3 gPack(HW / 1024, BATCH);
    k_pack_count<<<gPack, 256, 0, stream>>>(gt, packed, counts);

    dim3 gRed(4, CHAN, BATCH);
    k_reduce<<<gRed, 256, 0, stream>>>(img, packed, sums);

    k_means<<<(BATCH * CLASSES * CHAN + 255) / 256, 256, 0, stream>>>(sums, counts, means);

    dim3 gGat(16, CHAN / 4, BATCH);
    k_gather<<<gGat, 256, 0, stream>>>(packed, means, out);
}